// Round 10
// baseline (822.441 us; speedup 1.0000x reference)
//
#include <hip/hip_runtime.h>
#include <stdint.h>

// RNN1: B=4096,T=256,E=27,H=64.
// a_{t+1} = tanh(a_t @ Waa^T + x_t @ Wax^T + ba), x_t = word[:,t-1,:] (0 at t=0)
// y[:,t,:] = a_{t+1} @ Wy^T + by
//
// Round 10: INFO ROUND. Real kernel = r9 byte-identical (168us, passes).
// Plus two timing-only ablation kernels (no stores; asm sinks prevent DCE):
//   abl_core (T=768):  full compute core, no global/LDS I/O  -> 3*c_core
//   abl_pack (T=1024): 28-MFMA chain + cvtpk+mask only       -> 4*c_pack
// dur_us ~= 168 + 3*c_core + 4*c_pack; both variants slower than the real
// kernel so they surface in the top-5 rocprof rows with their own counters.
// Decision rules for next round are pre-committed in the session journal.

#define B_ 4096
#define T_ 256
#define E_ 27
#define H_ 64
#define WROW_ (H_ + E_)  // 91

typedef __bf16 bf16x8 __attribute__((ext_vector_type(8)));
typedef float f32x4 __attribute__((ext_vector_type(4)));
typedef unsigned int u32x4 __attribute__((ext_vector_type(4)));

struct __attribute__((packed)) f4a { float v[4]; };  // 4B-aligned global float4

static __device__ __forceinline__ unsigned pk2(float a, float b) {
  unsigned short ua = __builtin_bit_cast(unsigned short, (__bf16)a);
  unsigned short ub = __builtin_bit_cast(unsigned short, (__bf16)b);
  return (unsigned)ua | ((unsigned)ub << 16);
}
static __device__ __forceinline__ unsigned pkh(__bf16 a, __bf16 b) {
  unsigned short ua = __builtin_bit_cast(unsigned short, a);
  unsigned short ub = __builtin_bit_cast(unsigned short, b);
  return (unsigned)ua | ((unsigned)ub << 16);
}
// v_cvt_pk_bf16_f32: dst = [bf16(hi)|bf16(lo)], RNE (same as (__bf16) cast).
static __device__ __forceinline__ unsigned cvtpk(float lo, float hi) {
  unsigned r;
  asm("v_cvt_pk_bf16_f32 %0, %1, %2" : "=v"(r) : "v"(lo), "v"(hi));
  return r;
}
// lo-residual pack: t - f32(RNE16(t)) is exact in f32.
static __device__ __forceinline__ unsigned lopk(unsigned hpk, float t0, float t1) {
  const float f0 = __builtin_bit_cast(float, hpk << 16);
  const float f1 = __builtin_bit_cast(float, hpk & 0xffff0000u);
  return cvtpk(t0 - f0, t1 - f1);
}
static __device__ __forceinline__ float fast_tanh(float z) {
  // tanh(z) = 1 - 2/(exp(2z)+1); exp->inf / ->0 limits give +/-1 correctly
  float e = __expf(2.0f * z);
  float r = __builtin_amdgcn_rcpf(e + 1.0f);
  return __builtin_fmaf(-2.0f, r, 1.0f);
}
static __device__ __forceinline__ f32x4 MF(u32x4 a, u32x4 b, f32x4 c) {
  return __builtin_amdgcn_mfma_f32_16x16x32_bf16(
      __builtin_bit_cast(bf16x8, a), __builtin_bit_cast(bf16x8, b), c, 0, 0, 0);
}

// ---- shared weight-prep (identical math in all three kernels) ----
#define WEIGHT_PREP(NEED_Y)                                                   \
  u32x4 WH[4][2], WL[4][2], WX[4];                                            \
  f32x4 BAv[4];                                                               \
  _Pragma("unroll") for (int mt = 0; mt < 4; ++mt) {                          \
    const float* base = Wa + (16 * mt + p16) * WROW_;                         \
    _Pragma("unroll") for (int f = 0; f < 2; ++f) {                           \
      _Pragma("unroll") for (int v = 0; v < 4; ++v) {                         \
        const int j = 2 * v;                                                  \
        const int c = ((j < 4) ? (4 * lg + j) : (12 + 4 * lg + j)) + 32 * f;  \
        const float w0 = base[c], w1 = base[c + 1];                           \
        const __bf16 h0 = (__bf16)w0, h1 = (__bf16)w1;                        \
        WH[mt][f][v] = pkh(h0, h1);                                           \
        WL[mt][f][v] = pk2(w0 - (float)h0, w1 - (float)h1);                   \
      }                                                                       \
    }                                                                         \
    _Pragma("unroll") for (int v = 0; v < 4; ++v) {                           \
      const int e0 = 8 * lg + 2 * v, e1 = e0 + 1;                             \
      const float w0 = (e0 < E_) ? base[H_ + e0] : 0.f;                       \
      const float w1 = (e1 < E_) ? base[H_ + e1] : 0.f;                       \
      WX[mt][v] = pk2(w0, w1);                                                \
    }                                                                         \
  }                                                                           \
  _Pragma("unroll") for (int mt = 0; mt < 4; ++mt) {                          \
    f32x4 t;                                                                  \
    _Pragma("unroll") for (int r = 0; r < 4; ++r)                             \
        t[r] = ba[16 * mt + 4 * lg + r];                                      \
    BAv[mt] = t;                                                              \
  }

#define WEIGHT_PREP_Y()                                                       \
  u32x4 WY[2][2];                                                             \
  f32x4 BYv[2];                                                               \
  _Pragma("unroll") for (int my = 0; my < 2; ++my) {                          \
    const int e = 16 * my + p16;                                              \
    const bool valid = (e < E_);                                              \
    const float* rp = Wy + e * H_;                                            \
    _Pragma("unroll") for (int f = 0; f < 2; ++f) {                           \
      _Pragma("unroll") for (int v = 0; v < 4; ++v) {                         \
        const int j = 2 * v;                                                  \
        const int c = ((j < 4) ? (4 * lg + j) : (12 + 4 * lg + j)) + 32 * f;  \
        const float w0 = valid ? rp[c] : 0.f;                                 \
        const float w1 = valid ? rp[c + 1] : 0.f;                             \
        WY[my][f][v] = pk2(w0, w1);                                           \
      }                                                                       \
    }                                                                         \
  }                                                                           \
  _Pragma("unroll") for (int my = 0; my < 2; ++my) {                          \
    f32x4 t;                                                                  \
    _Pragma("unroll") for (int r = 0; r < 4; ++r) {                           \
      const int e = 16 * my + 4 * lg + r;                                     \
      t[r] = (e < E_) ? by[e] : 0.f;                                          \
    }                                                                         \
    BYv[my] = t;                                                              \
  }

#define PIN_STATE_WTS()                                                       \
  _Pragma("unroll") for (int mt = 0; mt < 4; ++mt) {                          \
    asm volatile("" : "+a"(WH[mt][0]), "+a"(WH[mt][1]), "+a"(WL[mt][0]),      \
                      "+a"(WL[mt][1]), "+a"(WX[mt]));                         \
  }                                                                           \
  asm volatile("" : "+v"(BAv[0]), "+v"(BAv[1]), "+v"(BAv[2]), "+v"(BAv[3]));

#define STATE_CHAIN()                                                         \
  f32x4 z0 = MF(WH[0][0], sH0, BAv[0]);                                       \
  f32x4 z1 = MF(WH[1][0], sH0, BAv[1]);                                       \
  f32x4 z2 = MF(WH[2][0], sH0, BAv[2]);                                       \
  f32x4 z3 = MF(WH[3][0], sH0, BAv[3]);                                       \
  z0 = MF(WH[0][1], sH1, z0);                                                 \
  z1 = MF(WH[1][1], sH1, z1);                                                 \
  z2 = MF(WH[2][1], sH1, z2);                                                 \
  z3 = MF(WH[3][1], sH1, z3);                                                 \
  z0 = MF(WL[0][0], sH0, z0);                                                 \
  z1 = MF(WL[1][0], sH0, z1);                                                 \
  z2 = MF(WL[2][0], sH0, z2);                                                 \
  z3 = MF(WL[3][0], sH0, z3);                                                 \
  z0 = MF(WL[0][1], sH1, z0);                                                 \
  z1 = MF(WL[1][1], sH1, z1);                                                 \
  z2 = MF(WL[2][1], sH1, z2);                                                 \
  z3 = MF(WL[3][1], sH1, z3);                                                 \
  z0 = MF(WX[0], xf, z0);                                                     \
  z1 = MF(WX[1], xf, z1);                                                     \
  z2 = MF(WX[2], xf, z2);                                                     \
  z3 = MF(WX[3], xf, z3);                                                     \
  z0 = MF(WH[0][0], sL0, z0);                                                 \
  z1 = MF(WH[1][0], sL0, z1);                                                 \
  z2 = MF(WH[2][0], sL0, z2);                                                 \
  z3 = MF(WH[3][0], sL0, z3);                                                 \
  z0 = MF(WH[0][1], sL1, z0);                                                 \
  z1 = MF(WH[1][1], sL1, z1);                                                 \
  z2 = MF(WH[2][1], sL1, z2);                                                 \
  z3 = MF(WH[3][1], sL1, z3);

#define TANH_PACK()                                                           \
  float tv[16];                                                               \
  _Pragma("unroll") for (int r = 0; r < 4; ++r) tv[r] = fast_tanh(z0[r]);     \
  _Pragma("unroll") for (int r = 0; r < 4; ++r) tv[4 + r] = fast_tanh(z1[r]); \
  _Pragma("unroll") for (int r = 0; r < 4; ++r) tv[8 + r] = fast_tanh(z2[r]); \
  _Pragma("unroll") for (int r = 0; r < 4; ++r) tv[12 + r] = fast_tanh(z3[r]);\
  sH0[0] = cvtpk(tv[0], tv[1]);                                               \
  sH0[1] = cvtpk(tv[2], tv[3]);                                               \
  sH0[2] = cvtpk(tv[4], tv[5]);                                               \
  sH0[3] = cvtpk(tv[6], tv[7]);                                               \
  sH1[0] = cvtpk(tv[8], tv[9]);                                               \
  sH1[1] = cvtpk(tv[10], tv[11]);                                             \
  sH1[2] = cvtpk(tv[12], tv[13]);                                             \
  sH1[3] = cvtpk(tv[14], tv[15]);

#define LO_SPLIT()                                                            \
  sL0[0] = lopk(sH0[0], tv[0], tv[1]);                                        \
  sL0[1] = lopk(sH0[1], tv[2], tv[3]);                                        \
  sL0[2] = lopk(sH0[2], tv[4], tv[5]);                                        \
  sL0[3] = lopk(sH0[3], tv[6], tv[7]);                                        \
  sL1[0] = lopk(sH1[0], tv[8], tv[9]);                                        \
  sL1[1] = lopk(sH1[1], tv[10], tv[11]);                                      \
  sL1[2] = lopk(sH1[2], tv[12], tv[13]);                                      \
  sL1[3] = lopk(sH1[3], tv[14], tv[15]);

// ============================ REAL KERNEL (r9) ============================
__global__ __launch_bounds__(64)
__attribute__((amdgpu_waves_per_eu(1, 1))) void rnn_fused(
    const float* __restrict__ word, const float* __restrict__ Wa,
    const float* __restrict__ ba, const float* __restrict__ Wy,
    const float* __restrict__ by, float* __restrict__ out) {
  __shared__ __align__(16) float xs[8][16][36];
  __shared__ __align__(16) float ys[4][16][36];

  const int lane = threadIdx.x;
  const int p16 = lane & 15;
  const int lg = lane >> 4;
  const int rb = (int)blockIdx.x * 16;

  const float* const wbase = word + (size_t)(rb + p16) * (T_ * E_);
  float* const obase = out + (size_t)(rb + p16) * (T_ * E_);

  {
    float* xz = &xs[0][0][0];
    for (int i = lane; i < 8 * 16 * 36; i += 64) xz[i] = 0.f;
  }

  WEIGHT_PREP(1)
  WEIGHT_PREP_Y()

  f32x4 Rg[2][7];
#define X_ISSUE(ts, P)                                                      \
  {                                                                         \
    const int st_ = (ts) + lg;                                              \
    if (st_ >= 1 && st_ < T_) {                                             \
      const float* p_ = wbase + (st_ - 1) * E_;                             \
      _Pragma("unroll") for (int c = 0; c < 7; ++c) {                       \
        asm volatile("global_load_dwordx4 %0, %1, off"                      \
                     : "=v"(Rg[P][c]) : "v"(p_ + 4 * c) : "memory");        \
      }                                                                     \
    }                                                                       \
  }
#define X_WRITE(ts, P)                                                      \
  {                                                                         \
    asm volatile("s_waitcnt vmcnt(0)" ::: "memory");                        \
    __builtin_amdgcn_sched_barrier(0);                                      \
    const int st_ = (ts) + lg;                                              \
    if (st_ >= 1 && st_ < T_) {                                             \
      float* d_ = &xs[st_ & 7][p16][0];                                     \
      _Pragma("unroll") for (int c = 0; c < 7; ++c)                         \
        *(f32x4*)(d_ + 4 * c) = Rg[P][c];                                   \
    }                                                                       \
    asm volatile("s_waitcnt lgkmcnt(0)" ::: "memory");                      \
    __builtin_amdgcn_sched_barrier(0);                                      \
  }
#define Y_FLUSH(tb)                                                         \
  {                                                                         \
    const float* s_ = &ys[lg][p16][0];                                      \
    float* d_ = obase + ((tb) + lg) * E_;                                   \
    _Pragma("unroll") for (int c = 0; c < 6; ++c) {                         \
      f32x4 v_ = *(const f32x4*)(s_ + 4 * c);                               \
      f4a o_;                                                               \
      o_.v[0] = v_[0]; o_.v[1] = v_[1]; o_.v[2] = v_[2]; o_.v[3] = v_[3];   \
      *(f4a*)(d_ + 4 * c) = o_;                                             \
    }                                                                       \
    f32x4 v6_ = *(const f32x4*)(s_ + 24);                                   \
    d_[24] = v6_[0]; d_[25] = v6_[1]; d_[26] = v6_[2];                      \
  }

  X_ISSUE(0, 0);
  X_WRITE(0, 0);
  X_ISSUE(4, 1);
  f32x4 xc0, xc1;
  {
    const float* xp = &xs[1][p16][8 * lg];
    xc0 = *(const f32x4*)xp;
    xc1 = *(const f32x4*)(xp + 4);
  }

  u32x4 sH0 = {0u, 0u, 0u, 0u}, sH1 = sH0, sL0 = sH0, sL1 = sH0;
  u32x4 xf = {0u, 0u, 0u, 0u};

#define STEP(t)                                                               \
  {                                                                           \
    STATE_CHAIN()                                                             \
    TANH_PACK()                                                               \
    xf[0] = cvtpk(xc0[0], xc0[1]);                                            \
    xf[1] = cvtpk(xc0[2], xc0[3]);                                            \
    xf[2] = cvtpk(xc1[0], xc1[1]);                                            \
    xf[3] = cvtpk(xc1[2], xc1[3]);                                            \
    if ((t) + 2 < T_) {                                                       \
      const float* xp_ = &xs[((t) + 2) & 7][p16][8 * lg];                     \
      xc0 = *(const f32x4*)xp_;                                               \
      xc1 = *(const f32x4*)(xp_ + 4);                                         \
    }                                                                         \
    LO_SPLIT()                                                                \
    f32x4 y0 = MF(WY[0][1], sH1, MF(WY[0][0], sH0, BYv[0]));                  \
    f32x4 y1 = MF(WY[1][1], sH1, MF(WY[1][0], sH0, BYv[1]));                  \
    *(f32x4*)&ys[(t) & 3][p16][4 * lg] = y0;                                  \
    *(f32x4*)&ys[(t) & 3][p16][16 + 4 * lg] = y1;                             \
  }

#define GROUP(t0, PW, PI)                                                     \
  {                                                                           \
    PIN_STATE_WTS()                                                           \
    asm volatile("" : "+a"(WY[0][0]), "+a"(WY[0][1]), "+a"(WY[1][0]),         \
                      "+a"(WY[1][1]));                                        \
    asm volatile("" : "+v"(BYv[0]), "+v"(BYv[1]));                            \
    X_WRITE((t0) + 4, PW);                                                    \
    X_ISSUE((t0) + 8, PI);                                                    \
    if ((t0) > 0) Y_FLUSH((t0) - 4);                                          \
    STEP(t0);                                                                 \
    STEP((t0) + 1);                                                           \
    STEP((t0) + 2);                                                           \
    STEP((t0) + 3);                                                           \
  }

  for (int t0 = 0; t0 < T_; t0 += 8) {
    GROUP(t0, 1, 0);
    GROUP(t0 + 4, 0, 1);
  }
  Y_FLUSH(T_ - 4);
#undef GROUP
#undef STEP
#undef X_ISSUE
#undef X_WRITE
#undef Y_FLUSH
}

// ===================== ABLATION 1: compute core, no I/O =====================
// T=768 (3x). Full STEP math (chain + tanh + packs + lo-split + y MFMAs);
// x from opaque registers; y sunk via asm. Measures c_core.
__global__ __launch_bounds__(64)
__attribute__((amdgpu_waves_per_eu(1, 1))) void abl_core(
    const float* __restrict__ word, const float* __restrict__ Wa,
    const float* __restrict__ ba, const float* __restrict__ Wy,
    const float* __restrict__ by) {
  const int lane = threadIdx.x;
  const int p16 = lane & 15;
  const int lg = lane >> 4;
  (void)word;

  WEIGHT_PREP(1)
  WEIGHT_PREP_Y()

  // opaque x source registers (stand-in for the LDS xc prefetch)
  f32x4 xc0, xc1;
#pragma unroll
  for (int r = 0; r < 4; ++r) { xc0[r] = ba[r] * 0.01f; xc1[r] = ba[4 + r] * 0.01f; }
  asm volatile("" : "+v"(xc0), "+v"(xc1));

  u32x4 sH0 = {0u, 0u, 0u, 0u}, sH1 = sH0, sL0 = sH0, sL1 = sH0;
  u32x4 xf = {0u, 0u, 0u, 0u};

#define STEPC()                                                               \
  {                                                                           \
    STATE_CHAIN()                                                             \
    TANH_PACK()                                                               \
    xf[0] = cvtpk(xc0[0], xc0[1]);                                            \
    xf[1] = cvtpk(xc0[2], xc0[3]);                                            \
    xf[2] = cvtpk(xc1[0], xc1[1]);                                            \
    xf[3] = cvtpk(xc1[2], xc1[3]);                                            \
    LO_SPLIT()                                                                \
    f32x4 y0 = MF(WY[0][1], sH1, MF(WY[0][0], sH0, BYv[0]));                  \
    f32x4 y1 = MF(WY[1][1], sH1, MF(WY[1][0], sH0, BYv[1]));                  \
    asm volatile("" :: "v"(y0), "v"(y1));                                     \
  }

  for (int t0 = 0; t0 < 768; t0 += 4) {
    PIN_STATE_WTS()
    asm volatile("" : "+a"(WY[0][0]), "+a"(WY[0][1]), "+a"(WY[1][0]),
                      "+a"(WY[1][1]));
    asm volatile("" : "+v"(BYv[0]), "+v"(BYv[1]));
    STEPC();
    STEPC();
    STEPC();
    STEPC();
  }
  asm volatile("" :: "v"(sH0), "v"(sH1), "v"(sL0), "v"(sL1));
#undef STEPC
}

// ================= ABLATION 2: MFMA chain + pack floor =================
// T=1024 (4x). 28 C-chained MFMAs + 8 cvtpk + 8 v_and (bounding mask).
// No tanh, no lo-split, no y. sL/xf are opaque loop-invariants. Measures
// c_pack = the irreducible MFMA-recurrence cost of this structure.
__global__ __launch_bounds__(64)
__attribute__((amdgpu_waves_per_eu(1, 1))) void abl_pack(
    const float* __restrict__ Wa, const float* __restrict__ ba) {
  const int lane = threadIdx.x;
  const int p16 = lane & 15;
  const int lg = lane >> 4;

  WEIGHT_PREP(0)

  u32x4 sH0 = {0u, 0u, 0u, 0u}, sH1 = sH0;
  u32x4 sL0 = {0x00800080u, 0x00800080u, 0x00800080u, 0x00800080u};  // tiny
  u32x4 sL1 = sL0;
  u32x4 xf = {0x3d803d80u, 0x3d803d80u, 0x3d803d80u, 0x3d803d80u};   // 0.0625
  asm volatile("" : "+v"(sL0), "+v"(sL1), "+v"(xf));
  const unsigned MSK = 0x3f803f80u;  // keep |state| < 2: finite forever

#define STEPP()                                                               \
  {                                                                           \
    STATE_CHAIN()                                                             \
    sH0[0] = cvtpk(z0[0], z0[1]) & MSK;                                       \
    sH0[1] = cvtpk(z0[2], z0[3]) & MSK;                                       \
    sH0[2] = cvtpk(z1[0], z1[1]) & MSK;                                       \
    sH0[3] = cvtpk(z1[2], z1[3]) & MSK;                                       \
    sH1[0] = cvtpk(z2[0], z2[1]) & MSK;                                       \
    sH1[1] = cvtpk(z2[2], z2[3]) & MSK;                                       \
    sH1[2] = cvtpk(z3[0], z3[1]) & MSK;                                       \
    sH1[3] = cvtpk(z3[2], z3[3]) & MSK;                                       \
  }

  for (int t0 = 0; t0 < 1024; t0 += 4) {
    PIN_STATE_WTS()
    STEPP();
    STEPP();
    STEPP();
    STEPP();
  }
  asm volatile("" :: "v"(sH0), "v"(sH1));
#undef STEPP
}

extern "C" void kernel_launch(void* const* d_in, const int* in_sizes, int n_in,
                              void* d_out, int out_size, void* d_ws,
                              size_t ws_size, hipStream_t stream) {
  const float* word = (const float*)d_in[0];
  const float* Wa = (const float*)d_in[1];
  const float* ba = (const float*)d_in[2];
  const float* Wy = (const float*)d_in[3];
  const float* by = (const float*)d_in[4];
  float* out = (float*)d_out;
  rnn_fused<<<dim3(B_ / 16), dim3(64), 0, stream>>>(word, Wa, ba, Wy, by, out);
  // timing-only ablation dispatches (write nothing; deterministic)
  abl_core<<<dim3(B_ / 16), dim3(64), 0, stream>>>(word, Wa, ba, Wy, by);
  abl_pack<<<dim3(B_ / 16), dim3(64), 0, stream>>>(Wa, ba);
}

// Round 11
// 523.854 us; speedup vs baseline: 1.5700x; 1.5700x over previous
//
#include <hip/hip_runtime.h>
#include <stdint.h>

// RNN1: B=4096,T=256,E=27,H=64.
// a_{t+1} = tanh(a_t @ Waa^T + x_t @ Wax^T + ba), x_t = word[:,t-1,:] (0 at t=0)
// y[:,t,:] = a_{t+1} @ Wy^T + by
//
// Round 11. Ablation (r10) measured: chain=543 cyc/step (depth-7 C-chain,
// ~78cyc/link), tanh/pack region=780, I/O~300. Two composable fixes:
//  (a) chain split into parallel 4+3 C-chains + f32x4 add (dep 543 -> ~350);
//  (b) TLP: 512-thread blocks = 8 waves = 2 waves/SIMD; each wave runs an
//      independent 16-row chain, so one wave's dep stalls are filled by the
//      other's issue. Requires <=256 regs/wave: LDS rings dropped (I/O
//      latency now TLP-hidden): compiler-visible depth-2 register prefetch
//      for x (r4-validated), direct scattered y stores (r5-validated).
//      ~140 VGPR + 96 AGPR (weight pins) = ~236 <= 256.
//
// TRANSPOSED per-wave design (validated r4-r10, absmax 0.0078125): each
// 64-lane wave owns 16 batch rows and the full H=64 chain; state^T = Waa@a^T,
// weights as A (rows m, k pre-permuted by sigma), state as B (n=batch).
// D layout (n=lane&15, m=4*lg+reg) IS the next step's sigma B-frag ->
// zero-cost feedback. sigma_f(lg,j) = (j<4 ? 4*lg+j : 12+4*lg+j) + 32*f.
// Numerics: split-bf16 state (hi+lo), 7 products; x and Wy single bf16.

#define B_ 4096
#define T_ 256
#define E_ 27
#define H_ 64
#define WROW_ (H_ + E_)  // 91

typedef __bf16 bf16x8 __attribute__((ext_vector_type(8)));
typedef float f32x4 __attribute__((ext_vector_type(4)));
typedef unsigned int u32x4 __attribute__((ext_vector_type(4)));

static __device__ __forceinline__ unsigned pk2(float a, float b) {
  unsigned short ua = __builtin_bit_cast(unsigned short, (__bf16)a);
  unsigned short ub = __builtin_bit_cast(unsigned short, (__bf16)b);
  return (unsigned)ua | ((unsigned)ub << 16);
}
static __device__ __forceinline__ unsigned pkh(__bf16 a, __bf16 b) {
  unsigned short ua = __builtin_bit_cast(unsigned short, a);
  unsigned short ub = __builtin_bit_cast(unsigned short, b);
  return (unsigned)ua | ((unsigned)ub << 16);
}
// v_cvt_pk_bf16_f32: dst = [bf16(hi)|bf16(lo)], RNE (same as (__bf16) cast).
static __device__ __forceinline__ unsigned cvtpk(float lo, float hi) {
  unsigned r;
  asm("v_cvt_pk_bf16_f32 %0, %1, %2" : "=v"(r) : "v"(lo), "v"(hi));
  return r;
}
// lo-residual pack: t - f32(RNE16(t)) is exact in f32.
static __device__ __forceinline__ unsigned lopk(unsigned hpk, float t0, float t1) {
  const float f0 = __builtin_bit_cast(float, hpk << 16);
  const float f1 = __builtin_bit_cast(float, hpk & 0xffff0000u);
  return cvtpk(t0 - f0, t1 - f1);
}
static __device__ __forceinline__ float fast_tanh(float z) {
  // tanh(z) = 1 - 2/(exp(2z)+1); exp->inf / ->0 limits give +/-1 correctly
  float e = __expf(2.0f * z);
  float r = __builtin_amdgcn_rcpf(e + 1.0f);
  return __builtin_fmaf(-2.0f, r, 1.0f);
}
static __device__ __forceinline__ f32x4 MF(u32x4 a, u32x4 b, f32x4 c) {
  return __builtin_amdgcn_mfma_f32_16x16x32_bf16(
      __builtin_bit_cast(bf16x8, a), __builtin_bit_cast(bf16x8, b), c, 0, 0, 0);
}

__global__ __launch_bounds__(512, 2)
__attribute__((amdgpu_waves_per_eu(2))) void rnn_fused(
    const float* __restrict__ word, const float* __restrict__ Wa,
    const float* __restrict__ ba, const float* __restrict__ Wy,
    const float* __restrict__ by, float* __restrict__ out) {
  const int tid = threadIdx.x;
  const int lane = tid & 63;
  const int wv = tid >> 6;    // wave id 0..7: independent 16-row chain
  const int p16 = lane & 15;  // batch row within group (n) / weight row (m)
  const int lg = lane >> 4;   // k-slot group
  const int rb = (int)blockIdx.x * 128 + wv * 16;

  const float* const wrow = word + (size_t)(rb + p16) * (T_ * E_);
  float* const pout = out + (size_t)(rb + p16) * (T_ * E_);

  // ---- weight fragments, pre-permuted by sigma (identical to r6-r10) ----
  u32x4 WH[4][2], WL[4][2], WX[4], WY[2][2];
  f32x4 BAv[4], BYv[2];
#pragma unroll
  for (int mt = 0; mt < 4; ++mt) {
    const float* base = Wa + (16 * mt + p16) * WROW_;
#pragma unroll
    for (int f = 0; f < 2; ++f) {
#pragma unroll
      for (int v = 0; v < 4; ++v) {
        const int j = 2 * v;
        const int c = ((j < 4) ? (4 * lg + j) : (12 + 4 * lg + j)) + 32 * f;
        const float w0 = base[c], w1 = base[c + 1];
        const __bf16 h0 = (__bf16)w0, h1 = (__bf16)w1;
        WH[mt][f][v] = pkh(h0, h1);
        WL[mt][f][v] = pk2(w0 - (float)h0, w1 - (float)h1);
      }
    }
#pragma unroll
    for (int v = 0; v < 4; ++v) {  // Wax, natural k = e
      const int e0 = 8 * lg + 2 * v, e1 = e0 + 1;
      const float w0 = (e0 < E_) ? base[H_ + e0] : 0.f;
      const float w1 = (e1 < E_) ? base[H_ + e1] : 0.f;
      WX[mt][v] = pk2(w0, w1);
    }
  }
#pragma unroll
  for (int my = 0; my < 2; ++my) {
    const int e = 16 * my + p16;
    const bool valid = (e < E_);
    const float* rp = Wy + e * H_;
#pragma unroll
    for (int f = 0; f < 2; ++f) {
#pragma unroll
      for (int v = 0; v < 4; ++v) {
        const int j = 2 * v;
        const int c = ((j < 4) ? (4 * lg + j) : (12 + 4 * lg + j)) + 32 * f;
        const float w0 = valid ? rp[c] : 0.f;
        const float w1 = valid ? rp[c + 1] : 0.f;
        WY[my][f][v] = pk2(w0, w1);
      }
    }
  }
#pragma unroll
  for (int mt = 0; mt < 4; ++mt) {
    f32x4 t;
#pragma unroll
    for (int r = 0; r < 4; ++r) t[r] = ba[16 * mt + 4 * lg + r];
    BAv[mt] = t;
  }
#pragma unroll
  for (int my = 0; my < 2; ++my) {
    f32x4 t;
#pragma unroll
    for (int r = 0; r < 4; ++r) {
      const int e = 16 * my + 4 * lg + r;
      t[r] = (e < E_) ? by[e] : 0.f;
    }
    BYv[my] = t;
  }

  // ---- x prefetch, depth 2 (compiler-visible; slack = 2 steps) ----
  // pf holds raw word row; packed into xf one step before use.
  float pf0[8], pf1[8];
#pragma unroll
  for (int k = 0; k < 8; ++k) {
    const int e = 8 * lg + k;
    pf0[k] = (e < E_) ? wrow[0 * E_ + 8 * lg + k] : 0.f;  // x_1
    pf1[k] = (e < E_) ? wrow[1 * E_ + 8 * lg + k] : 0.f;  // x_2
  }

  // ---- loop-carried state (sigma layout): a0 = 0, x_0 = 0 ----
  u32x4 sH0 = {0u, 0u, 0u, 0u}, sH1 = sH0, sL0 = sH0, sL1 = sH0;
  u32x4 xf = {0u, 0u, 0u, 0u};
  const f32x4 zf4 = {0.f, 0.f, 0.f, 0.f};

#define STEP(t, PF)                                                           \
  {                                                                           \
    /* 8 parallel C-chains: per mt chainA depth4 (WH0*sH0,WH1*sH1,WX*x,       \
       WH0*sL0) + chainB depth3 (WL0*sH0,WL1*sH1,WH1*sL1); z = A+B. */        \
    f32x4 a0 = MF(WH[0][0], sH0, BAv[0]);                                     \
    f32x4 a1 = MF(WH[1][0], sH0, BAv[1]);                                     \
    f32x4 a2 = MF(WH[2][0], sH0, BAv[2]);                                     \
    f32x4 a3 = MF(WH[3][0], sH0, BAv[3]);                                     \
    f32x4 b0 = MF(WL[0][0], sH0, zf4);                                        \
    f32x4 b1 = MF(WL[1][0], sH0, zf4);                                        \
    f32x4 b2 = MF(WL[2][0], sH0, zf4);                                        \
    f32x4 b3 = MF(WL[3][0], sH0, zf4);                                        \
    a0 = MF(WH[0][1], sH1, a0);                                               \
    a1 = MF(WH[1][1], sH1, a1);                                               \
    a2 = MF(WH[2][1], sH1, a2);                                               \
    a3 = MF(WH[3][1], sH1, a3);                                               \
    b0 = MF(WL[0][1], sH1, b0);                                               \
    b1 = MF(WL[1][1], sH1, b1);                                               \
    b2 = MF(WL[2][1], sH1, b2);                                               \
    b3 = MF(WL[3][1], sH1, b3);                                               \
    a0 = MF(WX[0], xf, a0);                                                   \
    a1 = MF(WX[1], xf, a1);                                                   \
    a2 = MF(WX[2], xf, a2);                                                   \
    a3 = MF(WX[3], xf, a3);                                                   \
    b0 = MF(WH[0][1], sL1, b0);                                               \
    b1 = MF(WH[1][1], sL1, b1);                                               \
    b2 = MF(WH[2][1], sL1, b2);                                               \
    b3 = MF(WH[3][1], sL1, b3);                                               \
    a0 = MF(WH[0][0], sL0, a0);                                               \
    a1 = MF(WH[1][0], sL0, a1);                                               \
    a2 = MF(WH[2][0], sL0, a2);                                               \
    a3 = MF(WH[3][0], sL0, a3);                                               \
    const f32x4 z0 = a0 + b0;                                                 \
    const f32x4 z1 = a1 + b1;                                                 \
    const f32x4 z2 = a2 + b2;                                                 \
    const f32x4 z3 = a3 + b3;                                                 \
    /* tanh + 1-instr RNE hi-pack -> new sH */                                \
    float tv[16];                                                             \
    _Pragma("unroll") for (int r = 0; r < 4; ++r) tv[r] = fast_tanh(z0[r]);   \
    _Pragma("unroll") for (int r = 0; r < 4; ++r) tv[4 + r] = fast_tanh(z1[r]);\
    _Pragma("unroll") for (int r = 0; r < 4; ++r) tv[8 + r] = fast_tanh(z2[r]);\
    _Pragma("unroll") for (int r = 0; r < 4; ++r) tv[12 + r] = fast_tanh(z3[r]);\
    sH0[0] = cvtpk(tv[0], tv[1]);                                             \
    sH0[1] = cvtpk(tv[2], tv[3]);                                             \
    sH0[2] = cvtpk(tv[4], tv[5]);                                             \
    sH0[3] = cvtpk(tv[6], tv[7]);                                             \
    sH1[0] = cvtpk(tv[8], tv[9]);                                             \
    sH1[1] = cvtpk(tv[10], tv[11]);                                           \
    sH1[2] = cvtpk(tv[12], tv[13]);                                           \
    sH1[3] = cvtpk(tv[14], tv[15]);                                           \
    /* off-path: pack x_{t+1} from PF, then refill PF with x_{t+3} */         \
    xf[0] = cvtpk(PF[0], PF[1]);                                              \
    xf[1] = cvtpk(PF[2], PF[3]);                                              \
    xf[2] = cvtpk(PF[4], PF[5]);                                              \
    xf[3] = cvtpk(PF[6], PF[7]);                                              \
    if ((t) + 3 < T_) { /* load word[t+2] = x_{t+3}, consumed at t+2 */       \
      const float* p_ = wrow + ((t) + 2) * E_;                                \
      _Pragma("unroll") for (int k = 0; k < 8; ++k) {                         \
        const int e = 8 * lg + k;                                             \
        PF[k] = (e < E_) ? p_[8 * lg + k] : 0.f;                              \
      }                                                                       \
    }                                                                         \
    /* lo-residual split in the shadow (sL consumed late next step) */        \
    sL0[0] = lopk(sH0[0], tv[0], tv[1]);                                      \
    sL0[1] = lopk(sH0[1], tv[2], tv[3]);                                      \
    sL0[2] = lopk(sH0[2], tv[4], tv[5]);                                      \
    sL0[3] = lopk(sH0[3], tv[6], tv[7]);                                      \
    sL1[0] = lopk(sH1[0], tv[8], tv[9]);                                      \
    sL1[1] = lopk(sH1[1], tv[10], tv[11]);                                    \
    sL1[2] = lopk(sH1[2], tv[12], tv[13]);                                    \
    sL1[3] = lopk(sH1[3], tv[14], tv[15]);                                    \
    /* y (off-path): C-chained pairs, direct scattered stores (TLP-hidden) */ \
    f32x4 y0 = MF(WY[0][1], sH1, MF(WY[0][0], sH0, BYv[0]));                  \
    f32x4 y1 = MF(WY[1][1], sH1, MF(WY[1][0], sH0, BYv[1]));                  \
    float* po = pout + (t)*E_;                                                \
    _Pragma("unroll") for (int r = 0; r < 4; ++r) po[4 * lg + r] = y0[r];     \
    _Pragma("unroll") for (int r = 0; r < 4; ++r) {                           \
      const int e = 16 + 4 * lg + r;                                          \
      if (e < E_) po[e] = y1[r];                                              \
    }                                                                         \
  }

  for (int t0 = 0; t0 < T_; t0 += 4) {
    // AGPR/VGPR pins (r6): weights resident in AGPRs, biases in VGPRs.
#pragma unroll
    for (int mt = 0; mt < 4; ++mt) {
      asm volatile("" : "+a"(WH[mt][0]), "+a"(WH[mt][1]), "+a"(WL[mt][0]),
                        "+a"(WL[mt][1]), "+a"(WX[mt]));
    }
    asm volatile("" : "+a"(WY[0][0]), "+a"(WY[0][1]), "+a"(WY[1][0]),
                      "+a"(WY[1][1]));
    asm volatile("" : "+v"(BAv[0]), "+v"(BAv[1]), "+v"(BAv[2]), "+v"(BAv[3]),
                      "+v"(BYv[0]), "+v"(BYv[1]));

    STEP(t0, pf0);
    STEP(t0 + 1, pf1);
    STEP(t0 + 2, pf0);
    STEP(t0 + 3, pf1);
  }
#undef STEP
}

extern "C" void kernel_launch(void* const* d_in, const int* in_sizes, int n_in,
                              void* d_out, int out_size, void* d_ws,
                              size_t ws_size, hipStream_t stream) {
  const float* word = (const float*)d_in[0];
  const float* Wa = (const float*)d_in[1];
  const float* ba = (const float*)d_in[2];
  const float* Wy = (const float*)d_in[3];
  const float* by = (const float*)d_in[4];
  float* out = (float*)d_out;
  rnn_fused<<<dim3(B_ / 128), dim3(512), 0, stream>>>(word, Wa, ba, Wy, by, out);
}

// Round 12
// 152.075 us; speedup vs baseline: 5.4081x; 3.4447x over previous
//
#include <hip/hip_runtime.h>
#include <stdint.h>

// RNN1: B=4096,T=256,E=27,H=64.
// a_{t+1} = tanh(a_t @ Waa^T + x_t @ Wax^T + ba), x_t = word[:,t-1,:] (0 at t=0)
// y[:,t,:] = a_{t+1} @ Wy^T + by
//
// Round 12. r11's 32-block grid starved 224 CUs (reverted: 256 blocks x 64).
// Lesson: latency-bound recurrence => wall = T x D; only shortening one
// step's serial latency D helps. r10 ablation: D = chain(543; 7 bf16-split
// MFMA terms) + tanh/pack(780; incl. lopk hi/lo machinery) + I/O(300).
// This round kills both big terms via SINGLE-TERM FP16 state (f16 mantissa
// 11 bits: per-step rounding ~3e-4, est absmax ~1e-2 < 3.4e-2 threshold):
//  - state path: 8 parallel MFMAs (4x[WH0*sF0 + zp] || 4x[WH1*sF1]) +
//    f32x4 add + tanh + RNE f16 pack. No lo-split, no lopk.
//  - x-term MFMA (zp = ba + WX*x_t) computed one step AHEAD, off-path.
//  - MFMA/step 32->16; VALU ~halved; trans unchanged.
// Skeleton (x/y LDS rings, group staging, AGPR pins) = r9 verbatim.
//
// TRANSPOSED per-wave design (r4-r10): wave owns 16 batch rows, full H=64
// chain; state^T = Waa @ a^T, weights as A (rows m, k pre-permuted by sigma),
// state as B (n=batch). D layout (n=lane&15, m=4*lg+reg) IS the next step's
// sigma B-frag -> zero-cost feedback. sigma_f(lg,j) = (j<4?4lg+j:12+4lg+j)+32f.
// (C/D and A/B fragment layouts are dtype-independent at 16x16x32 — doc.)

#define B_ 4096
#define T_ 256
#define E_ 27
#define H_ 64
#define WROW_ (H_ + E_)  // 91

typedef _Float16 f16x8 __attribute__((ext_vector_type(8)));
typedef float f32x4 __attribute__((ext_vector_type(4)));
typedef unsigned int u32x4 __attribute__((ext_vector_type(4)));

struct __attribute__((packed)) f4a { float v[4]; };  // 4B-aligned global float4

// RNE f32->f16 pair pack (v_cvt_f16_f32 x2 + pack; RNE = default cast).
static __device__ __forceinline__ unsigned pkf16(float a, float b) {
  _Float16 ha = (_Float16)a, hb = (_Float16)b;
  unsigned short ua = __builtin_bit_cast(unsigned short, ha);
  unsigned short ub = __builtin_bit_cast(unsigned short, hb);
  return (unsigned)ua | ((unsigned)ub << 16);
}
// RTZ packed f32x2->f16x2, 1 instr (x input only; one-shot rounding).
static __device__ __forceinline__ unsigned pkrtz(float a, float b) {
  unsigned r;
  asm("v_cvt_pkrtz_f16_f32 %0, %1, %2" : "=v"(r) : "v"(a), "v"(b));
  return r;
}
static __device__ __forceinline__ float fast_tanh(float z) {
  // tanh(z) = 1 - 2/(exp(2z)+1); exp->inf / ->0 limits give +/-1 correctly
  float e = __expf(2.0f * z);
  float r = __builtin_amdgcn_rcpf(e + 1.0f);
  return __builtin_fmaf(-2.0f, r, 1.0f);
}
static __device__ __forceinline__ f32x4 MFH(u32x4 a, u32x4 b, f32x4 c) {
  return __builtin_amdgcn_mfma_f32_16x16x32_f16(
      __builtin_bit_cast(f16x8, a), __builtin_bit_cast(f16x8, b), c, 0, 0, 0);
}

__global__ __launch_bounds__(64)
__attribute__((amdgpu_waves_per_eu(1, 1))) void rnn_fused(
    const float* __restrict__ word, const float* __restrict__ Wa,
    const float* __restrict__ ba, const float* __restrict__ Wy,
    const float* __restrict__ by, float* __restrict__ out) {
  // x ring: slot s holds x for step t (t%8==s) = word[:,t-1,:]; 36-pad ->
  // worst LDS aliasing 2-way (free). cols 28..35 stay zero forever.
  __shared__ __align__(16) float xs[8][16][36];
  __shared__ __align__(16) float ys[4][16][36];

  const int lane = threadIdx.x;
  const int p16 = lane & 15;  // batch row within group (n) / weight row (m)
  const int lg = lane >> 4;   // k-slot group / step-within-group for staging
  const int rb = (int)blockIdx.x * 16;

  const float* const wbase = word + (size_t)(rb + p16) * (T_ * E_);
  float* const obase = out + (size_t)(rb + p16) * (T_ * E_);

  {  // zero xs once (single wave: ordering vs later ds ops is automatic)
    float* xz = &xs[0][0][0];
    for (int i = lane; i < 8 * 16 * 36; i += 64) xz[i] = 0.f;
  }

  // ---- weight fragments (f16), pre-permuted by sigma ----
  u32x4 WH[4][2], WX[4], WY[2][2];
  f32x4 BAv[4], BYv[2];
#pragma unroll
  for (int mt = 0; mt < 4; ++mt) {
    const float* base = Wa + (16 * mt + p16) * WROW_;
#pragma unroll
    for (int f = 0; f < 2; ++f) {
#pragma unroll
      for (int v = 0; v < 4; ++v) {
        const int j = 2 * v;
        const int c = ((j < 4) ? (4 * lg + j) : (12 + 4 * lg + j)) + 32 * f;
        WH[mt][f][v] = pkf16(base[c], base[c + 1]);
      }
    }
#pragma unroll
    for (int v = 0; v < 4; ++v) {  // Wax, natural k = e
      const int e0 = 8 * lg + 2 * v, e1 = e0 + 1;
      const float w0 = (e0 < E_) ? base[H_ + e0] : 0.f;
      const float w1 = (e1 < E_) ? base[H_ + e1] : 0.f;
      WX[mt][v] = pkf16(w0, w1);
    }
  }
#pragma unroll
  for (int my = 0; my < 2; ++my) {
    const int e = 16 * my + p16;
    const bool valid = (e < E_);
    const float* rp = Wy + e * H_;
#pragma unroll
    for (int f = 0; f < 2; ++f) {
#pragma unroll
      for (int v = 0; v < 4; ++v) {
        const int j = 2 * v;
        const int c = ((j < 4) ? (4 * lg + j) : (12 + 4 * lg + j)) + 32 * f;
        const float w0 = valid ? rp[c] : 0.f;
        const float w1 = valid ? rp[c + 1] : 0.f;
        WY[my][f][v] = pkf16(w0, w1);
      }
    }
  }
#pragma unroll
  for (int mt = 0; mt < 4; ++mt) {
    f32x4 t;
#pragma unroll
    for (int r = 0; r < 4; ++r) t[r] = ba[16 * mt + 4 * lg + r];
    BAv[mt] = t;
  }
#pragma unroll
  for (int my = 0; my < 2; ++my) {
    f32x4 t;
#pragma unroll
    for (int r = 0; r < 4; ++r) {
      const int e = 16 * my + 4 * lg + r;
      t[r] = (e < E_) ? by[e] : 0.f;
    }
    BYv[my] = t;
  }

  // ---- x staging, double-buffered regs (r9-validated): lane owns step
  // ts+lg (word row ts+lg-1), 7 float4 chunks (chunk 6 overruns 1 float
  // within this batch row's T*E: staged rows <= 254). ----
  f32x4 Rg[2][7];
#define X_ISSUE(ts, P)                                                      \
  {                                                                         \
    const int st_ = (ts) + lg;                                              \
    if (st_ >= 1 && st_ < T_) {                                             \
      const float* p_ = wbase + (st_ - 1) * E_;                             \
      _Pragma("unroll") for (int c = 0; c < 7; ++c) {                       \
        asm volatile("global_load_dwordx4 %0, %1, off"                      \
                     : "=v"(Rg[P][c]) : "v"(p_ + 4 * c) : "memory");        \
      }                                                                     \
    }                                                                       \
  }
#define X_WRITE(ts, P)                                                      \
  {                                                                         \
    asm volatile("s_waitcnt vmcnt(0)" ::: "memory");                        \
    __builtin_amdgcn_sched_barrier(0);                                      \
    const int st_ = (ts) + lg;                                              \
    if (st_ >= 1 && st_ < T_) {                                             \
      float* d_ = &xs[st_ & 7][p16][0];                                     \
      _Pragma("unroll") for (int c = 0; c < 7; ++c)                         \
        *(f32x4*)(d_ + 4 * c) = Rg[P][c];                                   \
    }                                                                       \
    asm volatile("s_waitcnt lgkmcnt(0)" ::: "memory");                      \
    __builtin_amdgcn_sched_barrier(0);                                      \
  }
#define Y_FLUSH(tb)                                                         \
  {                                                                         \
    const float* s_ = &ys[lg][p16][0];                                      \
    float* d_ = obase + ((tb) + lg) * E_;                                   \
    _Pragma("unroll") for (int c = 0; c < 6; ++c) {                         \
      f32x4 v_ = *(const f32x4*)(s_ + 4 * c);                               \
      f4a o_;                                                               \
      o_.v[0] = v_[0]; o_.v[1] = v_[1]; o_.v[2] = v_[2]; o_.v[3] = v_[3];   \
      *(f4a*)(d_ + 4 * c) = o_;                                             \
    }                                                                       \
    f32x4 v6_ = *(const f32x4*)(s_ + 24);                                   \
    d_[24] = v6_[0]; d_[25] = v6_[1]; d_[26] = v6_[2];                      \
  }

  // ---- prologue: stage steps 1..3, issue 4..7; preload xc = x_1 ----
  X_ISSUE(0, 0);
  X_WRITE(0, 0);
  X_ISSUE(4, 1);
  f32x4 xc0, xc1;
  {
    const float* xp = &xs[1][p16][8 * lg];
    xc0 = *(const f32x4*)xp;
    xc1 = *(const f32x4*)(xp + 4);
  }

  // ---- loop-carried: sF (f16 state, sigma layout) = 0; zp = ba + WX*x_t
  // (x_0 = 0 -> zp = ba) ----
  u32x4 sF0 = {0u, 0u, 0u, 0u}, sF1 = sF0;
  f32x4 zp0 = BAv[0], zp1 = BAv[1], zp2 = BAv[2], zp3 = BAv[3];
  const f32x4 zf4 = {0.f, 0.f, 0.f, 0.f};

#define STEP(t)                                                               \
  {                                                                           \
    /* critical path: 8 parallel MFMAs -> add -> tanh -> RNE f16 pack */      \
    f32x4 a0 = MFH(WH[0][0], sF0, zp0);                                       \
    f32x4 a1 = MFH(WH[1][0], sF0, zp1);                                       \
    f32x4 a2 = MFH(WH[2][0], sF0, zp2);                                       \
    f32x4 a3 = MFH(WH[3][0], sF0, zp3);                                       \
    f32x4 b0 = MFH(WH[0][1], sF1, zf4);                                       \
    f32x4 b1 = MFH(WH[1][1], sF1, zf4);                                       \
    f32x4 b2 = MFH(WH[2][1], sF1, zf4);                                       \
    f32x4 b3 = MFH(WH[3][1], sF1, zf4);                                       \
    const f32x4 z0 = a0 + b0;                                                 \
    const f32x4 z1 = a1 + b1;                                                 \
    /* first half: tanh -> sF0 (frees next step's a-MFMAs early) */           \
    float tv[16];                                                             \
    _Pragma("unroll") for (int r = 0; r < 4; ++r) tv[r] = fast_tanh(z0[r]);   \
    _Pragma("unroll") for (int r = 0; r < 4; ++r) tv[4 + r] = fast_tanh(z1[r]);\
    sF0[0] = pkf16(tv[0], tv[1]);                                             \
    sF0[1] = pkf16(tv[2], tv[3]);                                             \
    sF0[2] = pkf16(tv[4], tv[5]);                                             \
    sF0[3] = pkf16(tv[6], tv[7]);                                             \
    const f32x4 z2 = a2 + b2;                                                 \
    const f32x4 z3 = a3 + b3;                                                 \
    _Pragma("unroll") for (int r = 0; r < 4; ++r) tv[8 + r] = fast_tanh(z2[r]);\
    _Pragma("unroll") for (int r = 0; r < 4; ++r) tv[12 + r] = fast_tanh(z3[r]);\
    sF1[0] = pkf16(tv[8], tv[9]);                                             \
    sF1[1] = pkf16(tv[10], tv[11]);                                           \
    sF1[2] = pkf16(tv[12], tv[13]);                                           \
    sF1[3] = pkf16(tv[14], tv[15]);                                           \
    /* off-path: x_{t+1} pack (RTZ, 1 instr/pair) + zp for next step */       \
    u32x4 xfn;                                                                \
    xfn[0] = pkrtz(xc0[0], xc0[1]);                                           \
    xfn[1] = pkrtz(xc0[2], xc0[3]);                                           \
    xfn[2] = pkrtz(xc1[0], xc1[1]);                                           \
    xfn[3] = pkrtz(xc1[2], xc1[3]);                                           \
    zp0 = MFH(WX[0], xfn, BAv[0]);                                            \
    zp1 = MFH(WX[1], xfn, BAv[1]);                                            \
    zp2 = MFH(WX[2], xfn, BAv[2]);                                            \
    zp3 = MFH(WX[3], xfn, BAv[3]);                                            \
    if ((t) + 2 < T_) { /* prefetch x_{t+2} from ring (full step of slack) */ \
      const float* xp_ = &xs[((t) + 2) & 7][p16][8 * lg];                     \
      xc0 = *(const f32x4*)xp_;                                               \
      xc1 = *(const f32x4*)(xp_ + 4);                                         \
    }                                                                         \
    /* y (off-path): uses NEW state; C-chained pairs; stash in LDS ring */    \
    f32x4 y0 = MFH(WY[0][1], sF1, MFH(WY[0][0], sF0, BYv[0]));                \
    f32x4 y1 = MFH(WY[1][1], sF1, MFH(WY[1][0], sF0, BYv[1]));                \
    *(f32x4*)&ys[(t) & 3][p16][4 * lg] = y0;                                  \
    *(f32x4*)&ys[(t) & 3][p16][16 + 4 * lg] = y1;                             \
  }

#define GROUP(t0, PW, PI)                                                     \
  {                                                                           \
    /* AGPR pins: weights resident in AGPRs; biases in VGPRs (r6 lesson). */  \
    _Pragma("unroll") for (int mt = 0; mt < 4; ++mt) {                        \
      asm volatile("" : "+a"(WH[mt][0]), "+a"(WH[mt][1]), "+a"(WX[mt]));      \
    }                                                                         \
    asm volatile("" : "+a"(WY[0][0]), "+a"(WY[0][1]), "+a"(WY[1][0]),         \
                      "+a"(WY[1][1]));                                        \
    asm volatile("" : "+v"(BAv[0]), "+v"(BAv[1]), "+v"(BAv[2]), "+v"(BAv[3]), \
                      "+v"(BYv[0]), "+v"(BYv[1]));                            \
    X_WRITE((t0) + 4, PW); /* stage steps t0+4..t0+7 (issued last group) */   \
    X_ISSUE((t0) + 8, PI); /* issue next group into the OTHER buffer */       \
    if ((t0) > 0) Y_FLUSH((t0) - 4);                                          \
    STEP(t0);                                                                 \
    STEP((t0) + 1);                                                           \
    STEP((t0) + 2);                                                           \
    STEP((t0) + 3);                                                           \
  }

  for (int t0 = 0; t0 < T_; t0 += 8) {
    GROUP(t0, 1, 0);      // write R1 (issued in prologue / prev odd group)
    GROUP(t0 + 4, 0, 1);  // write R0, issue R1
  }
  Y_FLUSH(T_ - 4);
#undef GROUP
#undef STEP
#undef X_ISSUE
#undef X_WRITE
#undef Y_FLUSH
}

extern "C" void kernel_launch(void* const* d_in, const int* in_sizes, int n_in,
                              void* d_out, int out_size, void* d_ws,
                              size_t ws_size, hipStream_t stream) {
  const float* word = (const float*)d_in[0];
  const float* Wa = (const float*)d_in[1];
  const float* ba = (const float*)d_in[2];
  const float* Wy = (const float*)d_in[3];
  const float* by = (const float*)d_in[4];
  float* out = (float*)d_out;
  rnn_fused<<<dim3(B_ / 16), dim3(64), 0, stream>>>(word, Wa, ba, Wy, by, out);
}